// Round 11
// baseline (100.691 us; speedup 1.0000x reference)
//
#include <hip/hip_runtime.h>
#include <hip/hip_bf16.h>
#include <math.h>

#define NN 4096
#define HH 256
#define G3 768
#define NHEADS 3
#define MAXE 128
#define ALPHA 0.2f

typedef __bf16 bf16;
typedef __attribute__((ext_vector_type(2))) __bf16 bf16x2;
typedef __attribute__((ext_vector_type(4))) __bf16 bf16x4;
typedef __attribute__((ext_vector_type(8))) __bf16 bf16x8;
typedef __attribute__((ext_vector_type(4))) float f32x4;

__device__ __forceinline__ void async_copy16(void* lds, const void* g) {
    __builtin_amdgcn_global_load_lds((const __attribute__((address_space(1))) void*)g,
                                     (__attribute__((address_space(3))) void*)lds, 16, 0, 0);
}

__device__ inline float lrelu(float x) { return x > 0.f ? x : ALPHA * x; }
__device__ inline float sigm(float x) { return 1.f / (1.f + __expf(-x)); }

// ================= prep: converts + transposes + gat_c + nnz zeroing =================
// [0,1024) h->bf16 | [1024,1792) GRU weights | [1792,1984) gat_W transpose
// [1984,1987) gat_c | [1987,1995) zero nnz_n/nnz_e
__global__ __launch_bounds__(256) void prep_k(
    const float* __restrict__ h,
    const float* __restrict__ eWih, const float* __restrict__ eWhh,
    const float* __restrict__ nWih, const float* __restrict__ nWhh,
    const float* __restrict__ gat_W, const float* __restrict__ gat_a,
    bf16* __restrict__ hb,
    bf16* __restrict__ Weib, bf16* __restrict__ Wehb,
    bf16* __restrict__ Wnib, bf16* __restrict__ Wnhb,
    bf16* __restrict__ Wtb, float* __restrict__ c0, float* __restrict__ c1,
    int* __restrict__ nnz_n, int* __restrict__ nnz_e) {
    __shared__ float tile[32][33];
    __shared__ float a_s[512];
    int b = blockIdx.x, t = threadIdx.x;
    if (b < 1024) {
        int idx = b * 256 + t;
        float4 v = *(const float4*)(h + (size_t)idx * 4);
        bf16x4 o = {(bf16)v.x, (bf16)v.y, (bf16)v.z, (bf16)v.w};
        *(bf16x4*)(hb + (size_t)idx * 4) = o;
    } else if (b < 1792) {
        int w = (b - 1024) / 192;
        int idx = ((b - 1024) % 192) * 256 + t;
        const float* in = w == 0 ? eWih : (w == 1 ? eWhh : (w == 2 ? nWih : nWhh));
        bf16* outp = w == 0 ? Weib : (w == 1 ? Wehb : (w == 2 ? Wnib : Wnhb));
        float4 v = *(const float4*)(in + (size_t)idx * 4);
        bf16x4 o = {(bf16)v.x, (bf16)v.y, (bf16)v.z, (bf16)v.w};
        *(bf16x4*)(outp + (size_t)idx * 4) = o;
    } else if (b < 1984) {
        int b2 = b - 1792;
        int hd = b2 >> 6, tl = b2 & 63;
        int k0 = (tl >> 3) * 32, n0 = (tl & 7) * 32;
        int tx = t % 32, ty = t / 32;
        const float* Wh = gat_W + (size_t)hd * HH * HH;
        for (int r = ty; r < 32; r += 8) tile[r][tx] = Wh[(size_t)(k0 + r) * HH + n0 + tx];
        __syncthreads();
        bf16* Wth = Wtb + (size_t)hd * HH * HH;
        for (int r = ty; r < 32; r += 8) Wth[(size_t)(n0 + r) * HH + k0 + tx] = (bf16)tile[tx][r];
    } else if (b < 1987) {
        int hd = b - 1984;
        a_s[t] = gat_a[(size_t)hd * 512 + t];
        a_s[t + 256] = gat_a[(size_t)hd * 512 + 256 + t];
        __syncthreads();
        const float* Wr = gat_W + (size_t)hd * HH * HH + (size_t)t * HH;
        f32x4 s0v = {}, s1v = {};
#pragma unroll 8
        for (int c4 = 0; c4 < 64; c4++) {
            f32x4 w = *(const f32x4*)(Wr + c4 * 4);
            f32x4 a0 = *(const f32x4*)(a_s + c4 * 4);
            f32x4 a1 = *(const f32x4*)(a_s + 256 + c4 * 4);
            s0v += w * a0;
            s1v += w * a1;
        }
        c0[hd * HH + t] = s0v[0] + s0v[1] + s0v[2] + s0v[3];
        c1[hd * HH + t] = s1v[0] + s1v[1] + s1v[2] + s1v[3];
    } else {
        int b2 = b - 1987;  // 0..7; first 4 -> nnz_n, last 4 -> nnz_e (4096 ints each, int4)
        int* dst = (b2 < 4) ? nnz_n : nnz_e;
        int idx = (b2 & 3) * 256 + t;
        ((int4*)dst)[idx] = make_int4(0, 0, 0, 0);
    }
}

// ================= grid-stride streaming compaction (no LDS, no barriers) =================
// 2048 blocks. Block b, iteration i in {0..3} handles one full row:
//   i=0: node row b | i=1: node row b+2048 | i=2: edge row b | i=3: edge row b+2048
// Lane strip = 16 contiguous floats (64 B). Per-row bucket via global atomicAdd(nnz[row]).
// 2-deep named-register prefetch keeps loads continuously in flight.
__device__ __forceinline__ void proc_chunk(f32x4 w0, f32x4 w1, f32x4 w2, f32x4 w3,
                                           int row, int col0,
                                           float* __restrict__ diagp,
                                           int* __restrict__ nnzp,
                                           int* __restrict__ colsp) {
    int kc = 0;
#define E1(V) { float a_ = (V); int col_ = col0 + ec_; ec_++; if (a_ != 0.f) { \
        if (col_ == row) diagp[row] = a_; else kc++; } }
    {
        int ec_ = 0;
        E1(w0[0]) E1(w0[1]) E1(w0[2]) E1(w0[3])
        E1(w1[0]) E1(w1[1]) E1(w1[2]) E1(w1[3])
        E1(w2[0]) E1(w2[1]) E1(w2[2]) E1(w2[3])
        E1(w3[0]) E1(w3[1]) E1(w3[2]) E1(w3[3])
    }
#undef E1
    if (kc) {
        int base = atomicAdd(nnzp + row, kc);
#define E2(V) { float a_ = (V); int col_ = col0 + ec_; ec_++; if (a_ != 0.f && col_ != row) { \
        if (base < MAXE) colsp[(size_t)row * MAXE + base] = (a_ > 0.f) ? (col_ + 1) : -(col_ + 1); base++; } }
        {
            int ec_ = 0;
            E2(w0[0]) E2(w0[1]) E2(w0[2]) E2(w0[3])
            E2(w1[0]) E2(w1[1]) E2(w1[2]) E2(w1[3])
            E2(w2[0]) E2(w2[1]) E2(w2[2]) E2(w2[3])
            E2(w3[0]) E2(w3[1]) E2(w3[2]) E2(w3[3])
        }
#undef E2
    }
}

__global__ __launch_bounds__(256) void compact_k(
    const float* __restrict__ node_adj, const float* __restrict__ edge_adj,
    float* __restrict__ dn, float* __restrict__ de,
    int* __restrict__ ccols_n, int* __restrict__ nnz_n,
    int* __restrict__ ccols_e, int* __restrict__ nnz_e) {
    int b = blockIdx.x, t = threadIdx.x;
    int col0 = t * 16;
    int r0 = b, r1 = b + 2048;

    const float* s0 = node_adj + ((size_t)r0 << 12) + col0;
    const float* s1 = node_adj + ((size_t)r1 << 12) + col0;
    const float* s2 = edge_adj + ((size_t)r0 << 12) + col0;
    const float* s3 = edge_adj + ((size_t)r1 << 12) + col0;

    f32x4 A0, A1, A2, A3, B0, B1, B2, B3;
#define LD(P_, SRC_) { P_##0 = *(const f32x4*)(SRC_); P_##1 = *(const f32x4*)((SRC_) + 4); \
                       P_##2 = *(const f32x4*)((SRC_) + 8); P_##3 = *(const f32x4*)((SRC_) + 12); }
    LD(A, s0)
    LD(B, s1)
    proc_chunk(A0, A1, A2, A3, r0, col0, dn, nnz_n, ccols_n);
    LD(A, s2)
    proc_chunk(B0, B1, B2, B3, r1, col0, dn, nnz_n, ccols_n);
    LD(B, s3)
    proc_chunk(A0, A1, A2, A3, r0, col0, de, nnz_e, ccols_e);
    proc_chunk(B0, B1, B2, B3, r1, col0, de, nnz_e, ccols_e);
#undef LD
}

// ================= node gather: nsup + fused gat_e (reads node CSR) =================
__global__ __launch_bounds__(256) void gather_k(
    const int* __restrict__ ccols_n, const int* __restrict__ nnz_n,
    const bf16* __restrict__ hb,
    const float* __restrict__ c0, const float* __restrict__ c1,
    bf16* __restrict__ nsupb, float* __restrict__ ep, float* __restrict__ em) {
    int i = blockIdx.x, t = threadIdx.x, lane = t & 63, wid = t >> 6;
    __shared__ int cols_s[MAXE];
    __shared__ float part[6][4];
    int n = nnz_n[i];
    if (n > MAXE) n = MAXE;
    if (t < n) cols_s[t] = ccols_n[(size_t)i * MAXE + t];
    __syncthreads();
    float accp = 0.f, accm = 0.f;
#pragma unroll 8
    for (int kk = 0; kk < n; kk++) {
        int c = cols_s[kk];  // LDS broadcast
        int j = (c > 0 ? c : -c) - 1;
        float hv = (float)hb[(size_t)j * HH + t];
        if (c > 0) accp += hv; else accm += hv;
    }
    nsupb[(size_t)i * HH + t] = (bf16)(accp - accm);
    float u[6];
#pragma unroll
    for (int hd = 0; hd < NHEADS; hd++) {
        float a0 = c0[hd * HH + t], a1 = c1[hd * HH + t];
        u[hd * 2]     = accp * a0 + accm * a1;
        u[hd * 2 + 1] = accm * a0 + accp * a1;
    }
#pragma unroll
    for (int vv = 0; vv < 6; vv++)
#pragma unroll
        for (int off = 32; off; off >>= 1) u[vv] += __shfl_xor(u[vv], off);
    if (lane == 0)
#pragma unroll
        for (int vv = 0; vv < 6; vv++) part[vv][wid] = u[vv];
    __syncthreads();
    if (t < 6) {
        float s = part[t][0] + part[t][1] + part[t][2] + part[t][3];
        int hd = t >> 1;
        ((t & 1) == 0 ? ep : em)[(size_t)hd * NN + i] = lrelu(s);
    }
}

// ================= bf16 MFMA GEMM (m97 structure), z-batched up to 3 =================
__global__ __launch_bounds__(256) void gemm_bt(
    const bf16* __restrict__ A0, const bf16* __restrict__ A1, const bf16* __restrict__ A2,
    const bf16* __restrict__ B0, const bf16* __restrict__ B1, const bf16* __restrict__ B2,
    bf16* __restrict__ C0, bf16* __restrict__ C1, bf16* __restrict__ C2) {
    __shared__ bf16 a_s[128 * 32];
    __shared__ bf16 b_s[128 * 32];
    int z = blockIdx.z;
    const bf16* A = z == 0 ? A0 : (z == 1 ? A1 : A2);
    const bf16* Bt = z == 0 ? B0 : (z == 1 ? B1 : B2);
    bf16* C = z == 0 ? C0 : (z == 1 ? C1 : C2);

    int tid = threadIdx.x;
    int lane = tid & 63, wid = tid >> 6;
    int wr = (wid >> 1) * 64, wc = (wid & 1) * 64;
    int i0 = blockIdx.x * 128;
    int c0n = blockIdx.y * 128;

    f32x4 acc[4][4] = {};
    int kq = (lane >> 4) * 8;

    for (int k0 = 0; k0 < 256; k0 += 32) {
        __syncthreads();
#pragma unroll
        for (int it = 0; it < 2; it++) {
            int ch = it * 256 + tid;
            int r = ch >> 2, c16 = ch & 3;
            async_copy16(&a_s[ch * 8], A + (size_t)(i0 + r) * 256 + k0 + c16 * 8);
            async_copy16(&b_s[ch * 8], Bt + (size_t)(c0n + r) * 256 + k0 + c16 * 8);
        }
        __syncthreads();
        bf16x8 af[4], bf[4];
#pragma unroll
        for (int m = 0; m < 4; m++) af[m] = *(const bf16x8*)&a_s[(wr + m * 16 + (lane & 15)) * 32 + kq];
#pragma unroll
        for (int n = 0; n < 4; n++) bf[n] = *(const bf16x8*)&b_s[(wc + n * 16 + (lane & 15)) * 32 + kq];
#pragma unroll
        for (int m = 0; m < 4; m++)
#pragma unroll
            for (int n = 0; n < 4; n++)
                acc[m][n] = __builtin_amdgcn_mfma_f32_16x16x32_bf16(af[m], bf[n], acc[m][n], 0, 0, 0);
    }
#pragma unroll
    for (int m = 0; m < 4; m++) {
#pragma unroll
        for (int n = 0; n < 4; n++) {
            int row = i0 + wr + m * 16 + (lane >> 4) * 4;
            int col = c0n + wc + n * 16 + (lane & 15);
#pragma unroll
            for (int j = 0; j < 4; j++)
                C[(size_t)(row + j) * G3 + col] = (bf16)acc[m][n][j];
        }
    }
}

// ================= GAT sparse output =================
__global__ __launch_bounds__(256) void gat_out(
    const int* __restrict__ ccols_e, const int* __restrict__ nnz_e,
    const float* __restrict__ ep, const float* __restrict__ em,
    const bf16* __restrict__ hWb2, bf16* __restrict__ esupb) {
    int i = blockIdx.x, t = threadIdx.x;
    __shared__ int cols_s[MAXE];
    __shared__ int js[MAXE];
    __shared__ float w_s[NHEADS][MAXE];
    __shared__ f32x4 sacc[NHEADS][64];
    int n = nnz_e[i];
    if (n > MAXE) n = MAXE;
    if (t < n) {
        int c = ccols_e[(size_t)i * MAXE + t];
        cols_s[t] = c;
        js[t] = (c > 0 ? c : -c) - 1;
    }
    __syncthreads();
    int wid = t >> 6, lane = t & 63;
    if (wid < NHEADS) {
        int hd = wid;
        const float* eph = ep + (size_t)hd * NN;
        const float* emh = em + (size_t)hd * NN;
        float v0 = -1e30f, v1 = -1e30f;
        if (lane < n)      { int c = cols_s[lane];      v0 = c > 0 ? eph[js[lane]]      : emh[js[lane]]; }
        if (lane + 64 < n) { int c = cols_s[lane + 64]; v1 = c > 0 ? eph[js[lane + 64]] : emh[js[lane + 64]]; }
        float mx = fmaxf(v0, v1);
#pragma unroll
        for (int off = 32; off; off >>= 1) mx = fmaxf(mx, __shfl_xor(mx, off));
        float w0 = (lane < n) ? __expf(v0 - mx) : 0.f;
        float w1 = (lane + 64 < n) ? __expf(v1 - mx) : 0.f;
        float s = w0 + w1;
#pragma unroll
        for (int off = 32; off; off >>= 1) s += __shfl_xor(s, off);
        float inv = 1.f / s;
        if (lane < n)      w_s[hd][lane]      = (cols_s[lane] > 0 ? w0 : -w0) * inv;
        if (lane + 64 < n) w_s[hd][lane + 64] = (cols_s[lane + 64] > 0 ? w1 : -w1) * inv;
    }
    __syncthreads();
    if (t < 192) {
        int hd = t >> 6, g = t & 63;
        const bf16* base = hWb2 + (size_t)hd * HH + g * 4;
        f32x4 acc = {};
#pragma unroll 4
        for (int k = 0; k < n; k++) {
            float w = w_s[hd][k];
            bf16x4 hv = *(const bf16x4*)(base + (size_t)js[k] * G3);
            f32x4 f = {(float)hv[0], (float)hv[1], (float)hv[2], (float)hv[3]};
            acc += w * f;
        }
        sacc[hd][g] = acc;
    }
    __syncthreads();
    if (t < 64) {
        f32x4 s = (sacc[0][t] + sacc[1][t] + sacc[2][t]) * (1.f / 3.f);
        bf16x4 o = {(bf16)s[0], (bf16)s[1], (bf16)s[2], (bf16)s[3]};
        *(bf16x4*)(esupb + (size_t)i * HH + t * 4) = o;
    }
}

// ================= both GRU cells + final combine, writes d_out =================
__global__ __launch_bounds__(256) void gru_both(
    const bf16* __restrict__ gie, const bf16* __restrict__ ghe,
    const bf16* __restrict__ gin, const bf16* __restrict__ ghn,
    const float* __restrict__ ebih, const float* __restrict__ ebhh,
    const float* __restrict__ nbih, const float* __restrict__ nbhh,
    const float* __restrict__ h, const float* __restrict__ dnv, const float* __restrict__ dev,
    float* __restrict__ out) {
    int sub = threadIdx.x >> 7, tc = threadIdx.x & 127;
    int i = blockIdx.x * 2 + sub;
    int c = tc * 2;
    size_t gb = (size_t)i * G3;
    float2 hv = *(const float2*)(h + (size_t)i * HH + c);
    float De = dev[i], Dn = dnv[i];

#define LD2(p, off) (*(const bf16x2*)((p) + gb + (off) + c))
#define BI2(p, off) (*(const float2*)((p) + (off) + c))
    bf16x2 eir = LD2(gie, 0), eiz = LD2(gie, 256), ein = LD2(gie, 512);
    bf16x2 ehr = LD2(ghe, 0), ehz = LD2(ghe, 256), ehn = LD2(ghe, 512);
    bf16x2 nir = LD2(gin, 0), niz = LD2(gin, 256), nin = LD2(gin, 512);
    bf16x2 nhr = LD2(ghn, 0), nhz = LD2(ghn, 256), nhn = LD2(ghn, 512);
    float2 ebr = BI2(ebih, 0), ebz = BI2(ebih, 256), ebn = BI2(ebih, 512);
    float2 eb2r = BI2(ebhh, 0), eb2z = BI2(ebhh, 256), eb2n = BI2(ebhh, 512);
    float2 nbr = BI2(nbih, 0), nbz = BI2(nbih, 256), nbn = BI2(nbih, 512);
    float2 nb2r = BI2(nbhh, 0), nb2z = BI2(nbhh, 256), nb2n = BI2(nbhh, 512);
#undef LD2
#undef BI2

    float res[2];
#pragma unroll
    for (int j = 0; j < 2; j++) {
        float hj = j == 0 ? hv.x : hv.y;
        float r = sigm(((float)eir[j] + (j ? ebr.y : ebr.x)) + ((float)ehr[j] + (j ? eb2r.y : eb2r.x)));
        float z = sigm(((float)eiz[j] + (j ? ebz.y : ebz.x)) + ((float)ehz[j] + (j ? eb2z.y : eb2z.x)));
        float nv = tanhf(((float)ein[j] + (j ? ebn.y : ebn.x)) + r * ((float)ehn[j] + (j ? eb2n.y : eb2n.x)));
        float eo = (1.f - z) * nv + z * hj;
        float r2 = sigm(((float)nir[j] + (j ? nbr.y : nbr.x)) + ((float)nhr[j] + (j ? nb2r.y : nb2r.x)));
        float z2 = sigm(((float)niz[j] + (j ? nbz.y : nbz.x)) + ((float)nhz[j] + (j ? nb2z.y : nb2z.x)));
        float nv2 = tanhf(((float)nin[j] + (j ? nbn.y : nbn.x)) + r2 * ((float)nhn[j] + (j ? nb2n.y : nb2n.x)));
        float no = (1.f - z2) * nv2 + z2 * hj;
        res[j] = De * eo + Dn * no;
    }
    *(float2*)(out + (size_t)i * HH + c) = make_float2(res[0], res[1]);
}

extern "C" void kernel_launch(void* const* d_in, const int* in_sizes, int n_in,
                              void* d_out, int out_size, void* d_ws, size_t ws_size,
                              hipStream_t stream) {
    const float* h        = (const float*)d_in[0];
    const float* node_adj = (const float*)d_in[1];
    const float* edge_adj = (const float*)d_in[2];
    const float* gat_W    = (const float*)d_in[3];
    const float* gat_a    = (const float*)d_in[4];
    const float* e_Wih    = (const float*)d_in[5];
    const float* e_Whh    = (const float*)d_in[6];
    const float* e_bih    = (const float*)d_in[7];
    const float* e_bhh    = (const float*)d_in[8];
    const float* n_Wih    = (const float*)d_in[9];
    const float* n_Whh    = (const float*)d_in[10];
    const float* n_bih    = (const float*)d_in[11];
    const float* n_bhh    = (const float*)d_in[12];
    float* out = (float*)d_out;

    char* ws = (char*)d_ws;
    size_t off = 0;
    auto alloc = [&](size_t bytes) { char* p = ws + off; off += (bytes + 255) & ~(size_t)255; return p; };

    float* ep    = (float*)alloc((size_t)NHEADS * NN * 4);
    float* em    = (float*)alloc((size_t)NHEADS * NN * 4);
    float* c0    = (float*)alloc((size_t)NHEADS * HH * 4);
    float* c1    = (float*)alloc((size_t)NHEADS * HH * 4);
    float* dn    = (float*)alloc(NN * 4);
    float* de    = (float*)alloc(NN * 4);
    bf16*  hb    = (bf16*)alloc((size_t)NN * HH * 2);
    bf16*  nsupb = (bf16*)alloc((size_t)NN * HH * 2);
    bf16*  esupb = (bf16*)alloc((size_t)NN * HH * 2);
    bf16*  hWb2  = (bf16*)alloc((size_t)NN * G3 * 2);
    bf16*  gie   = (bf16*)alloc((size_t)NN * G3 * 2);
    bf16*  ghe   = (bf16*)alloc((size_t)NN * G3 * 2);
    bf16*  gin   = (bf16*)alloc((size_t)NN * G3 * 2);
    bf16*  ghn   = (bf16*)alloc((size_t)NN * G3 * 2);
    bf16*  Weib  = (bf16*)alloc((size_t)G3 * HH * 2);
    bf16*  Wehb  = (bf16*)alloc((size_t)G3 * HH * 2);
    bf16*  Wnib  = (bf16*)alloc((size_t)G3 * HH * 2);
    bf16*  Wnhb  = (bf16*)alloc((size_t)G3 * HH * 2);
    bf16*  Wtb   = (bf16*)alloc((size_t)NHEADS * HH * HH * 2);
    int*   ccols_n = (int*)alloc((size_t)NN * MAXE * 4);
    int*   nnz_n   = (int*)alloc(NN * 4);
    int*   ccols_e = (int*)alloc((size_t)NN * MAXE * 4);
    int*   nnz_e   = (int*)alloc(NN * 4);

    dim3 b256(256);

    // 1. prep: converts + gat_W transpose + gat_c + zero nnz counters
    prep_k<<<1995, b256, 0, stream>>>(h, e_Wih, e_Whh, n_Wih, n_Whh, gat_W, gat_a,
                                      hb, Weib, Wehb, Wnib, Wnhb, Wtb, c0, c1,
                                      nnz_n, nnz_e);

    // 2. grid-stride streaming compaction of both adjacency matrices
    compact_k<<<2048, b256, 0, stream>>>(node_adj, edge_adj, dn, de,
                                         ccols_n, nnz_n, ccols_e, nnz_e);

    // 3. gemmA z=3: hW (3 heads concat N=768), gh_e, gh_n (only needs prep)
    gemm_bt<<<dim3(NN / 128, G3 / 128, 3), b256, 0, stream>>>(
        hb, hb, hb, Wtb, Wehb, Wnhb, hWb2, ghe, ghn);

    // 4. node gather: nsup + gat_e
    gather_k<<<NN, b256, 0, stream>>>(ccols_n, nnz_n, hb, c0, c1, nsupb, ep, em);

    // 5. GAT sparse attention output
    gat_out<<<NN, b256, 0, stream>>>(ccols_e, nnz_e, ep, em, hWb2, esupb);

    // 6. gemmB z=2: gi_e, gi_n
    gemm_bt<<<dim3(NN / 128, G3 / 128, 2), b256, 0, stream>>>(
        nsupb, esupb, esupb, Weib, Wnib, Wnib, gie, gin, gin);

    // 7. both GRUs + combine -> out
    gru_both<<<NN / 2, b256, 0, stream>>>(gie, ghe, gin, ghn,
                                          e_bih, e_bhh, n_bih, n_bhh,
                                          h, dn, de, out);
}